// Round 3
// baseline (110.128 us; speedup 1.0000x reference)
//
#include <hip/hip_runtime.h>

typedef float f32x2 __attribute__((ext_vector_type(2)));
typedef float f32x4 __attribute__((ext_vector_type(4)));

#define BB 4
#define NN 8192
#define NPTS (BB * NN)               // 32768 points per cloud
#define TILE 256
#define JSPLIT 8                     // j-range splits per (b,dir)
#define JRANGE (NN / JSPLIT)         // 1024 j per block
#define SELF_PER_BLOCK (TILE * 2)    // 512 self points per block (2 per thread)
#define STILES (NN / SELF_PER_BLOCK) // 16

// Pair-packed transform. For point pair (2jp, 2jp+1):
//   t[2jp+0] = (-2x0, -2x1, -2y0, -2y1)
//   t[2jp+1] = (-2z0, -2z1, |p0|^2, |p1|^2)
// This layout makes {q.x for j0,j1} etc. land in adjacent lanes of a f32x2,
// so the main loop's fma chains map directly onto v_pk_fma_f32.
__global__ __launch_bounds__(256) void transform_kernel(
    const float* __restrict__ p1, const float* __restrict__ p2,
    f32x4* __restrict__ t1, f32x4* __restrict__ t2, float* __restrict__ out)
{
    const int jp = blockIdx.x * 256 + threadIdx.x;   // global pair id
    if (jp == 0) out[0] = 0.f;                       // init accumulator for reduce
    {
        const float* p = p1 + (size_t)jp * 6;
        const float x0=p[0], y0=p[1], z0=p[2], x1=p[3], y1=p[4], z1=p[5];
        t1[2*jp+0] = f32x4{-2.f*x0, -2.f*x1, -2.f*y0, -2.f*y1};
        t1[2*jp+1] = f32x4{-2.f*z0, -2.f*z1,
                           fmaf(x0,x0,fmaf(y0,y0,z0*z0)),
                           fmaf(x1,x1,fmaf(y1,y1,z1*z1))};
    }
    {
        const float* p = p2 + (size_t)jp * 6;
        const float x0=p[0], y0=p[1], z0=p[2], x1=p[3], y1=p[4], z1=p[5];
        t2[2*jp+0] = f32x4{-2.f*x0, -2.f*x1, -2.f*y0, -2.f*y1};
        t2[2*jp+1] = f32x4{-2.f*z0, -2.f*z1,
                           fmaf(x0,x0,fmaf(y0,y0,z0*z0)),
                           fmaf(x1,x1,fmaf(y1,y1,z1*z1))};
    }
}

// No LDS, no barriers: the q stream is wave-uniform (address depends only on
// blockIdx + loop counter) -> broadcast L2 loads / s_load. Each thread owns 2
// self points; each block scans a 1024-j window; per-block partial mins
// (already +|a|^2, clamped) written to pm[bz][jsplit][self].
__global__ __launch_bounds__(TILE, 4) void chamfer_main(
    const float* __restrict__ p1, const float* __restrict__ p2,
    const f32x4* __restrict__ t1, const f32x4* __restrict__ t2,
    float* __restrict__ pm)
{
    const int bz = blockIdx.y, b = bz >> 1, dir = bz & 1;
    const int tilei = blockIdx.x >> 3;   // 0..15
    const int js    = blockIdx.x & 7;    // 0..7

    const float* selfp = dir ? p2 : p1;
    const f32x4* tq    = dir ? t1 : t2;  // dir=0: other=p2 -> t2? (see below)
    // careful: dir=0 means self=p1, other=p2 -> use t2
    const f32x4* q = (dir ? t1 : t2) + (size_t)b * NN + (size_t)js * JRANGE;
    (void)tq;

    const int i0 = tilei * SELF_PER_BLOCK + threadIdx.x;
    const float* sp0 = selfp + ((size_t)b * NN + i0) * 3;
    const float a0x = sp0[0],        a0y = sp0[1],        a0z = sp0[2];
    const float a1x = sp0[TILE*3+0], a1y = sp0[TILE*3+1], a1z = sp0[TILE*3+2];

    const f32x2 A0x = {a0x, a0x}, A0y = {a0y, a0y}, A0z = {a0z, a0z};
    const f32x2 A1x = {a1x, a1x}, A1y = {a1y, a1y}, A1z = {a1z, a1z};

    f32x2 m0 = {3.4e38f, 3.4e38f};
    f32x2 m1 = m0;

    #pragma unroll 4
    for (int k = 0; k < JRANGE / 2; ++k) {
        const f32x4 A = q[2*k+0];        // (x0,x1,y0,y1)
        const f32x4 B = q[2*k+1];        // (z0,z1,w0,w1)
        const f32x2 qx = A.xy, qy = A.zw, qz = B.xy, qw = B.zw;
        const f32x2 v0 = __builtin_elementwise_fma(A0x, qx,
                         __builtin_elementwise_fma(A0y, qy,
                         __builtin_elementwise_fma(A0z, qz, qw)));
        const f32x2 v1 = __builtin_elementwise_fma(A1x, qx,
                         __builtin_elementwise_fma(A1y, qy,
                         __builtin_elementwise_fma(A1z, qz, qw)));
        m0 = __builtin_elementwise_min(m0, v0);
        m1 = __builtin_elementwise_min(m1, v1);
    }

    const float a20 = fmaf(a0x,a0x, fmaf(a0y,a0y, a0z*a0z));
    const float a21 = fmaf(a1x,a1x, fmaf(a1y,a1y, a1z*a1z));
    const float r0 = fmaxf(fminf(m0.x, m0.y) + a20, 0.f);
    const float r1 = fmaxf(fminf(m1.x, m1.y) + a21, 0.f);

    float* dst = pm + ((size_t)bz * JSPLIT + js) * NN;
    dst[i0]        = r0;
    dst[i0 + TILE] = r1;
}

// Final: min over the JSPLIT partials per self point, then mean-sum.
// mean(d12)+mean(d21) = sum(all 2*B*N mins) / (B*N) since N == M.
__global__ __launch_bounds__(256) void reduce_kernel(
    const float* __restrict__ pm, float* __restrict__ out)
{
    const int s  = blockIdx.x * 256 + threadIdx.x;   // 0..2*B*N-1
    const int bz = s >> 13;                          // NN = 8192
    const int i  = s & (NN - 1);
    const float* base = pm + (size_t)bz * JSPLIT * NN + i;
    float m = base[0];
    #pragma unroll
    for (int k = 1; k < JSPLIT; ++k) m = fminf(m, base[(size_t)k * NN]);

    float ssum = m;
    #pragma unroll
    for (int off = 32; off; off >>= 1) ssum += __shfl_down(ssum, off);

    __shared__ float wsum[4];
    const int lane = threadIdx.x & 63, wid = threadIdx.x >> 6;
    if (lane == 0) wsum[wid] = ssum;
    __syncthreads();
    if (threadIdx.x == 0) {
        const float t = wsum[0] + wsum[1] + wsum[2] + wsum[3];
        atomicAdd(out, t * (1.f / (float)NPTS));
    }
}

extern "C" void kernel_launch(void* const* d_in, const int* in_sizes, int n_in,
                              void* d_out, int out_size, void* d_ws, size_t ws_size,
                              hipStream_t stream)
{
    const float* p1 = (const float*)d_in[0];
    const float* p2 = (const float*)d_in[1];
    f32x4* t1 = (f32x4*)d_ws;            // NPTS f32x4 = 512 KB
    f32x4* t2 = t1 + NPTS;               // 512 KB
    float* pm = (float*)(t2 + NPTS);     // 2*BB*JSPLIT*NN floats = 2 MB
    float* out = (float*)d_out;

    transform_kernel<<<NPTS/2/256, 256, 0, stream>>>(p1, p2, t1, t2, out);

    dim3 grid(STILES * JSPLIT, BB * 2);  // 128 x 8 = 1024 blocks
    chamfer_main<<<grid, TILE, 0, stream>>>(p1, p2, t1, t2, pm);

    reduce_kernel<<<2 * NPTS / 256, 256, 0, stream>>>(pm, out);
}